// Round 4
// baseline (2503.506 us; speedup 1.0000x reference)
//
#include <hip/hip_runtime.h>
#include <math.h>

#define BB   32
#define TT   512
#define DIM  512
#define HID  1024
#define QQ   8
#define CC   256
#define DD   256
#define BT   16384
#define EPSB 1e-5f

typedef _Float16 half4 __attribute__((ext_vector_type(4)));
typedef _Float16 half8 __attribute__((ext_vector_type(8)));
typedef float f32x4 __attribute__((ext_vector_type(4)));

#define GLOAD_LDS16(g, l)                                                      \
  __builtin_amdgcn_global_load_lds(                                            \
      (const __attribute__((address_space(1))) void*)(g),                      \
      (__attribute__((address_space(3))) void*)(l), 16, 0, 0)

// ---------------------------------------------------------------------------
// Transpose x (B, DIM, T) -> xt (B*T, DIM)
// ---------------------------------------------------------------------------
__global__ __launch_bounds__(256) void transpose_xt(const float* __restrict__ x,
                                                    float* __restrict__ xt) {
  __shared__ float tile[32][33];
  int tx = threadIdx.x, ty = threadIdx.y;
  int b = blockIdx.z;
  int t0 = blockIdx.x * 32, c0 = blockIdx.y * 32;
  const float* xb = x + (size_t)b * DIM * TT;
#pragma unroll
  for (int j = 0; j < 32; j += 8)
    tile[ty + j][tx] = xb[(size_t)(c0 + ty + j) * TT + (t0 + tx)];
  __syncthreads();
  float* xtb = xt + ((size_t)b * TT) * DIM;
#pragma unroll
  for (int j = 0; j < 32; j += 8)
    xtb[(size_t)(t0 + ty + j) * DIM + (c0 + tx)] = tile[tx][ty + j];
}

// ---------------------------------------------------------------------------
// fp32 NT GEMM, BK=8 single-buffer LDS + REGISTER PREFETCH of the next tile:
// barrier -> store(prefetched) -> barrier -> issue loads for kb+8 (+fused BN
// transform) -> 512-FMA block. The FMA block hides the global-load latency
// that round 3 paid on the critical path (VALUBusy 57%).
// C[m,n] = sum_k T(A[m,k]) * W[n,k] + bias[n]; fused column-stats epilogue.
// ---------------------------------------------------------------------------
__global__ __launch_bounds__(256) void sgemm_f32(
    const float* __restrict__ A, int lda, const float* __restrict__ W, int ldw,
    const float* __restrict__ bias, float* __restrict__ C, int ldc, int K,
    const float* __restrict__ tsc, const float* __restrict__ tsh, int trelu,
    float* __restrict__ stats, int N) {
  __shared__ float As[8][128];
  __shared__ float Ws[8][128];
  const int tid = threadIdx.x;
  const int m0 = blockIdx.y * 128, n0 = blockIdx.x * 128;
  const int lr = tid >> 1, lk = (tid & 1) << 2;
  const float* Ap = A + (size_t)(m0 + lr) * lda + lk;
  const float* Wp = W + (size_t)(n0 + lr) * ldw + lk;
  const int tm = (tid >> 4) << 3, tn = (tid & 15) << 3;

  float acc[8][8];
#pragma unroll
  for (int i = 0; i < 8; i++)
#pragma unroll
    for (int j = 0; j < 8; j++) acc[i][j] = 0.f;

  float4 av, wv;

#define LOADTR(kb)                                                             \
  {                                                                            \
    av = *(const float4*)(Ap + (kb));                                          \
    wv = *(const float4*)(Wp + (kb));                                          \
    if (tsc) {                                                                 \
      float4 c0 = *(const float4*)(tsc + (kb) + lk);                           \
      float4 h0 = *(const float4*)(tsh + (kb) + lk);                           \
      av.x = fmaf(av.x, c0.x, h0.x); av.y = fmaf(av.y, c0.y, h0.y);            \
      av.z = fmaf(av.z, c0.z, h0.z); av.w = fmaf(av.w, c0.w, h0.w);            \
      if (trelu) {                                                             \
        av.x = fmaxf(av.x, 0.f); av.y = fmaxf(av.y, 0.f);                      \
        av.z = fmaxf(av.z, 0.f); av.w = fmaxf(av.w, 0.f);                      \
      }                                                                        \
    }                                                                          \
  }

  LOADTR(0);
  for (int kb = 0; kb < K; kb += 8) {
    __syncthreads();
    As[lk + 0][lr] = av.x; As[lk + 1][lr] = av.y;
    As[lk + 2][lr] = av.z; As[lk + 3][lr] = av.w;
    Ws[lk + 0][lr] = wv.x; Ws[lk + 1][lr] = wv.y;
    Ws[lk + 2][lr] = wv.z; Ws[lk + 3][lr] = wv.w;
    __syncthreads();
    if (kb + 8 < K) LOADTR(kb + 8);
#pragma unroll
    for (int k = 0; k < 8; ++k) {
      float a[8], b[8];
      *(float4*)(a) = *(const float4*)(&As[k][tm]);
      *(float4*)(a + 4) = *(const float4*)(&As[k][tm + 4]);
      *(float4*)(b) = *(const float4*)(&Ws[k][tn]);
      *(float4*)(b + 4) = *(const float4*)(&Ws[k][tn + 4]);
#pragma unroll
      for (int i = 0; i < 8; i++)
#pragma unroll
        for (int j = 0; j < 8; j++) acc[i][j] = fmaf(a[i], b[j], acc[i][j]);
    }
  }
#undef LOADTR

  float bv[8], s1[8], s2[8];
#pragma unroll
  for (int j = 0; j < 8; j++) {
    bv[j] = bias ? bias[n0 + tn + j] : 0.f;
    s1[j] = 0.f; s2[j] = 0.f;
  }
#pragma unroll
  for (int i = 0; i < 8; i++) {
    float v[8];
#pragma unroll
    for (int j = 0; j < 8; j++) {
      v[j] = acc[i][j] + bv[j];
      s1[j] += v[j];
      s2[j] = fmaf(v[j], v[j], s2[j]);
    }
    float* Cp = C + (size_t)(m0 + tm + i) * ldc + (n0 + tn);
    float4 o;
    o.x = v[0]; o.y = v[1]; o.z = v[2]; o.w = v[3];
    *(float4*)Cp = o;
    o.x = v[4]; o.y = v[5]; o.z = v[6]; o.w = v[7];
    *(float4*)(Cp + 4) = o;
  }
  if (stats) {
#pragma unroll
    for (int j = 0; j < 8; j++) {
      s1[j] += __shfl_xor(s1[j], 16); s1[j] += __shfl_xor(s1[j], 32);
      s2[j] += __shfl_xor(s2[j], 16); s2[j] += __shfl_xor(s2[j], 32);
    }
    if ((tid & 48) == 0) {
#pragma unroll
      for (int j = 0; j < 8; j++) {
        atomicAdd(&stats[n0 + tn + j], s1[j]);
        atomicAdd(&stats[N + n0 + tn + j], s2[j]);
      }
    }
  }
}

// ---------------------------------------------------------------------------
// Fused logits GEMM (BM=64, BN=256=C, K=256) + dual argmax epilogue, with the
// same register-prefetch structure.
// ---------------------------------------------------------------------------
__global__ __launch_bounds__(256) void sgemm_logits(
    const float* __restrict__ Z, const float* __restrict__ codebook,
    const float* __restrict__ u, const float* __restrict__ log_temps,
    int qbase, float* __restrict__ out_idx, int* __restrict__ idx2) {
  __shared__ float As[8][64];
  __shared__ float Ws[8][256];
  const int tid = threadIdx.x;
  const int qz = blockIdx.z;
  const int q = qbase + qz;
  const int m0 = blockIdx.y * 64;
  const float* A = Z + qz * CC;                      // row stride 1024
  const float* W = codebook + (size_t)q * CC * DD;   // (256, 256)

  const int arow = tid >> 2, ak = (tid & 3) << 1;
  const float* Ap = A + (size_t)(m0 + arow) * 1024 + ak;
  const float* WpR = W + (size_t)tid * DD;
  const int tm = (tid >> 4) << 2, tn = (tid & 15) << 4;

  float acc[4][16];
#pragma unroll
  for (int i = 0; i < 4; i++)
#pragma unroll
    for (int j = 0; j < 16; j++) acc[i][j] = 0.f;

  float2 av;
  float4 w0, w1;
#define LLOAD(kb)                                                              \
  {                                                                            \
    av = *(const float2*)(Ap + (kb));                                          \
    w0 = *(const float4*)(WpR + (kb));                                         \
    w1 = *(const float4*)(WpR + (kb) + 4);                                     \
  }

  LLOAD(0);
  for (int kb = 0; kb < CC; kb += 8) {
    __syncthreads();
    As[ak + 0][arow] = av.x; As[ak + 1][arow] = av.y;
    Ws[0][tid] = w0.x; Ws[1][tid] = w0.y;
    Ws[2][tid] = w0.z; Ws[3][tid] = w0.w;
    Ws[4][tid] = w1.x; Ws[5][tid] = w1.y;
    Ws[6][tid] = w1.z; Ws[7][tid] = w1.w;
    __syncthreads();
    if (kb + 8 < CC) LLOAD(kb + 8);
#pragma unroll
    for (int k = 0; k < 8; ++k) {
      float a[4], b[16];
      *(float4*)(a) = *(const float4*)(&As[k][tm]);
      *(float4*)(b) = *(const float4*)(&Ws[k][tn]);
      *(float4*)(b + 4) = *(const float4*)(&Ws[k][tn + 4]);
      *(float4*)(b + 8) = *(const float4*)(&Ws[k][tn + 8]);
      *(float4*)(b + 12) = *(const float4*)(&Ws[k][tn + 12]);
#pragma unroll
      for (int i = 0; i < 4; i++)
#pragma unroll
        for (int j = 0; j < 16; j++) acc[i][j] = fmaf(a[i], b[j], acc[i][j]);
    }
  }
#undef LLOAD

  const float scale = expf(-log_temps[q]);
#pragma unroll
  for (int i = 0; i < 4; i++) {
    const int row = m0 + tm + i;
    const float* urow = u + (size_t)row * (QQ * CC) + q * CC + tn;
    float bvv = -INFINITY; int bi = 0;
    float gv = -INFINITY; int gi = 0;
#pragma unroll
    for (int j4 = 0; j4 < 4; j4++) {
      float4 uv = *(const float4*)(urow + j4 * 4);
      float uu[4] = {uv.x, uv.y, uv.z, uv.w};
#pragma unroll
      for (int jj = 0; jj < 4; jj++) {
        int j = j4 * 4 + jj;
        int c = tn + j;
        float v = acc[i][j];
        if (v > bvv) { bvv = v; bi = c; }
        float uc = fminf(fmaxf(uu[jj], 1e-9f), 1.0f);
        float g = -logf(-logf(uc) + 1e-20f);
        float y = fmaf(v, scale, g);
        if (y > gv) { gv = y; gi = c; }
      }
    }
#pragma unroll
    for (int off = 1; off < 16; off <<= 1) {
      float b2 = __shfl_xor(bvv, off); int bi2 = __shfl_xor(bi, off);
      if (b2 > bvv || (b2 == bvv && bi2 < bi)) { bvv = b2; bi = bi2; }
      float g2 = __shfl_xor(gv, off); int gi2 = __shfl_xor(gi, off);
      if (g2 > gv || (g2 == gv && gi2 < gi)) { gv = g2; gi = gi2; }
    }
    if ((tid & 15) == 0) {
      out_idx[(size_t)row * QQ + q] = (float)bi;
      idx2[(size_t)row * QQ + q] = gi;
    }
  }
}

// ---------------------------------------------------------------------------
// FP16 MFMA NT GEMM (m97 structure): 128x128 tile, BK=32, global_load_lds x16B
// ---------------------------------------------------------------------------
__global__ __launch_bounds__(256, 2) void hgemm_nt(
    const _Float16* __restrict__ A, const _Float16* __restrict__ W,
    const float* __restrict__ bias, float* __restrict__ C, int ldc, int K,
    float* __restrict__ stats, int N) {
  __shared__ _Float16 Al[4 * 128 * 8];   // [kpart][row][8]
  __shared__ _Float16 Bl[4 * 128 * 8];
  const int tid = threadIdx.x;
  const int l = tid & 63;
  const int w = tid >> 6;
  const int m0 = blockIdx.y * 128, n0 = blockIdx.x * 128;
  const int wrow = (w >> 1) * 64, wcol = (w & 1) * 64;

  const int s0 = tid, s1 = tid + 256;
  const int r0 = s0 & 127, kp0 = s0 >> 7;
  const int r1 = s1 & 127, kp1 = s1 >> 7;
  const _Float16* Ag0 = A + (size_t)(m0 + r0) * K + kp0 * 8;
  const _Float16* Ag1 = A + (size_t)(m0 + r1) * K + kp1 * 8;
  const _Float16* Wg0 = W + (size_t)(n0 + r0) * K + kp0 * 8;
  const _Float16* Wg1 = W + (size_t)(n0 + r1) * K + kp1 * 8;
  _Float16* Al0 = &Al[s0 * 8]; _Float16* Al1 = &Al[s1 * 8];
  _Float16* Bl0 = &Bl[s0 * 8]; _Float16* Bl1 = &Bl[s1 * 8];

  f32x4 acc[4][4] = {};

  for (int kb = 0; kb < K; kb += 32) {
    __syncthreads();
    GLOAD_LDS16(Ag0 + kb, Al0);
    GLOAD_LDS16(Ag1 + kb, Al1);
    GLOAD_LDS16(Wg0 + kb, Bl0);
    GLOAD_LDS16(Wg1 + kb, Bl1);
    __syncthreads();
    half8 af[4], bf[4];
#pragma unroll
    for (int i = 0; i < 4; i++)
      af[i] = *(const half8*)&Al[(((l >> 4) << 7) + wrow + i * 16 + (l & 15)) * 8];
#pragma unroll
    for (int j = 0; j < 4; j++)
      bf[j] = *(const half8*)&Bl[(((l >> 4) << 7) + wcol + j * 16 + (l & 15)) * 8];
#pragma unroll
    for (int i = 0; i < 4; i++)
#pragma unroll
      for (int j = 0; j < 4; j++)
        acc[i][j] = __builtin_amdgcn_mfma_f32_16x16x32_f16(af[i], bf[j],
                                                           acc[i][j], 0, 0, 0);
  }

#pragma unroll
  for (int j = 0; j < 4; j++) {
    const int col = n0 + wcol + j * 16 + (l & 15);
    const float bb = bias[col];
    float s1v = 0.f, s2v = 0.f;
#pragma unroll
    for (int i = 0; i < 4; i++) {
#pragma unroll
      for (int r = 0; r < 4; r++) {
        float v = acc[i][j][r] + bb;
        const int row = m0 + wrow + i * 16 + ((l >> 4) << 2) + r;
        C[(size_t)row * ldc + col] = v;
        s1v += v;
        s2v = fmaf(v, v, s2v);
      }
    }
    if (stats) {
      s1v += __shfl_xor(s1v, 16); s1v += __shfl_xor(s1v, 32);
      s2v += __shfl_xor(s2v, 16); s2v += __shfl_xor(s2v, 32);
      if (l < 16) {
        atomicAdd(&stats[col], s1v);
        atomicAdd(&stats[N + col], s2v);
      }
    }
  }
}

// ---------------------------------------------------------------------------
// BatchNorm helpers
// ---------------------------------------------------------------------------
__global__ __launch_bounds__(256) void colstats(const float* __restrict__ h, int N,
                                                float* __restrict__ sums) {
  int col = blockIdx.x * 256 + threadIdx.x;
  size_t base = (size_t)blockIdx.y * 256 * N + col;
  float s = 0.f, s2 = 0.f;
  for (int r = 0; r < 256; r++) {
    float v = h[base + (size_t)r * N];
    s += v;
    s2 = fmaf(v, v, s2);
  }
  atomicAdd(&sums[col], s);
  atomicAdd(&sums[N + col], s2);
}

__global__ __launch_bounds__(256) void bn_finalize(const float* __restrict__ sums,
                                                   const float* __restrict__ gamma,
                                                   const float* __restrict__ beta,
                                                   float* __restrict__ ss, int N) {
  int n = blockIdx.x * 256 + threadIdx.x;
  if (n >= N) return;
  const float invM = 1.0f / (float)BT;
  float mean = sums[n] * invM;
  float var = sums[N + n] * invM - mean * mean;
  float sc = gamma[n] / sqrtf(var + EPSB);
  ss[n] = sc;
  ss[N + n] = beta[n] - mean * sc;
}

// fp32 h -> f16 out with BN scale/shift (+optional relu)
__global__ __launch_bounds__(256) void bn_apply_f16(const float* __restrict__ h,
                                                    const float* __restrict__ ss,
                                                    int nmask, int N, long n4,
                                                    int relu,
                                                    _Float16* __restrict__ o) {
  long stride = (long)gridDim.x * 256;
  for (long i = (long)blockIdx.x * 256 + threadIdx.x; i < n4; i += stride) {
    int col = (int)((i << 2) & nmask);
    float4 v = ((const float4*)h)[i];
    float4 sc = *(const float4*)(ss + col);
    float4 sh = *(const float4*)(ss + N + col);
    v.x = fmaf(v.x, sc.x, sh.x); v.y = fmaf(v.y, sc.y, sh.y);
    v.z = fmaf(v.z, sc.z, sh.z); v.w = fmaf(v.w, sc.w, sh.w);
    if (relu) {
      v.x = fmaxf(v.x, 0.f); v.y = fmaxf(v.y, 0.f);
      v.z = fmaxf(v.z, 0.f); v.w = fmaxf(v.w, 0.f);
    }
    half4 hv;
    hv.x = (_Float16)v.x; hv.y = (_Float16)v.y;
    hv.z = (_Float16)v.z; hv.w = (_Float16)v.w;
    ((half4*)o)[i] = hv;
  }
}

__global__ __launch_bounds__(256) void conv_f16(const float* __restrict__ in,
                                                _Float16* __restrict__ o, int n4) {
  int i = blockIdx.x * 256 + threadIdx.x;
  if (i >= n4) return;
  float4 v = ((const float4*)in)[i];
  half4 hv;
  hv.x = (_Float16)v.x; hv.y = (_Float16)v.y;
  hv.z = (_Float16)v.z; hv.w = (_Float16)v.w;
  ((half4*)o)[i] = hv;
}

// ---------------------------------------------------------------------------
// emb[bt, d] = sum_q codebook[q, idx2[bt,q], d]
// ---------------------------------------------------------------------------
__global__ __launch_bounds__(256) void emb_gather(const float* __restrict__ cb,
                                                  const int* __restrict__ idx2,
                                                  float* __restrict__ emb) {
  __shared__ int k[QQ];
  int bt = blockIdx.x;
  int d = threadIdx.x;
  if (d < QQ) k[d] = idx2[bt * QQ + d];
  __syncthreads();
  float s = 0.f;
#pragma unroll
  for (int q = 0; q < QQ; q++) s += cb[((size_t)(q * CC + k[q])) * DD + d];
  emb[(size_t)bt * DD + d] = s;
}

// ---------------------------------------------------------------------------
// commit loss
// ---------------------------------------------------------------------------
__global__ __launch_bounds__(256) void loss_kernel(const float* __restrict__ xr,
                                                   const float* __restrict__ xt,
                                                   float* __restrict__ out) {
  const long n4 = (long)BT * DIM / 4;
  float s = 0.f;
  long stride = (long)gridDim.x * 256;
  for (long i = (long)blockIdx.x * 256 + threadIdx.x; i < n4; i += stride) {
    float4 a = ((const float4*)xr)[i];
    float4 b = ((const float4*)xt)[i];
    float dx = a.x - b.x, dy = a.y - b.y, dz = a.z - b.z, dw = a.w - b.w;
    s = fmaf(dx, dx, s); s = fmaf(dy, dy, s);
    s = fmaf(dz, dz, s); s = fmaf(dw, dw, s);
  }
#pragma unroll
  for (int off = 32; off > 0; off >>= 1) s += __shfl_down(s, off);
  __shared__ float red[4];
  if ((threadIdx.x & 63) == 0) red[threadIdx.x >> 6] = s;
  __syncthreads();
  if (threadIdx.x == 0)
    atomicAdd(out, (red[0] + red[1] + red[2] + red[3]) * (1.0f / (float)(BT * DIM)));
}

// ---------------------------------------------------------------------------
// Workspace layout (float offsets)
// ---------------------------------------------------------------------------
static const size_t OF_XT = 0;
static const size_t OF_R1 = OF_XT + (size_t)BT * DIM;
static const size_t OF_R2 = OF_R1 + (size_t)BT * HID;
static const size_t OF_EMBH = OF_R2 + (size_t)BT * HID;
static const size_t OF_HB = OF_EMBH + (size_t)BT * DD / 2;
static const size_t OF_W0H = OF_HB + (size_t)BT * HID / 2;
static const size_t OF_W1H = OF_W0H + (size_t)HID * DD / 2;
static const size_t OF_WFH = OF_W1H + (size_t)HID * HID / 2;
static const size_t OF_I2 = OF_WFH + (size_t)DIM * HID / 2;
static const size_t OF_ST = OF_I2 + (size_t)BT * QQ;
static const size_t OF_SS0 = OF_ST + 4096;
static const size_t OF_SS1 = OF_SS0 + 2048;
static const size_t OF_SSD = OF_SS1 + 2048;
static const size_t OF_SD0 = OF_SSD + 1024;
static const size_t OF_SD1 = OF_SD0 + 2048;

extern "C" void kernel_launch(void* const* d_in, const int* in_sizes, int n_in,
                              void* d_out, int out_size, void* d_ws, size_t ws_size,
                              hipStream_t stream) {
  const float* x        = (const float*)d_in[0];
  const float* u        = (const float*)d_in[1];
  const float* codebook = (const float*)d_in[2];
  const float* log_temps= (const float*)d_in[3];
  const float* enc_w0   = (const float*)d_in[4];
  const float* enc_b0   = (const float*)d_in[5];
  const float* enc_g0   = (const float*)d_in[6];
  const float* enc_be0  = (const float*)d_in[7];
  const float* enc_w1   = (const float*)d_in[8];
  const float* enc_b1   = (const float*)d_in[9];
  const float* enc_g1   = (const float*)d_in[10];
  const float* enc_be1  = (const float*)d_in[11];
  const float* enc_wo   = (const float*)d_in[12];
  const float* enc_bo   = (const float*)d_in[13];
  const float* dec_g    = (const float*)d_in[14];
  const float* dec_be   = (const float*)d_in[15];
  const float* dec_w0   = (const float*)d_in[16];
  const float* dec_b0   = (const float*)d_in[17];
  const float* dec_g0   = (const float*)d_in[18];
  const float* dec_be0  = (const float*)d_in[19];
  const float* dec_w1   = (const float*)d_in[20];
  const float* dec_b1   = (const float*)d_in[21];
  const float* dec_g1   = (const float*)d_in[22];
  const float* dec_be1  = (const float*)d_in[23];
  const float* fin_w    = (const float*)d_in[24];
  const float* fin_b    = (const float*)d_in[25];

  float* ws = (float*)d_ws;
  float* xt = ws + OF_XT;
  float* R1 = ws + OF_R1;
  float* R2 = ws + OF_R2;
  _Float16* embh = (_Float16*)(ws + OF_EMBH);
  _Float16* hbuf = (_Float16*)(ws + OF_HB);
  _Float16* w0h = (_Float16*)(ws + OF_W0H);
  _Float16* w1h = (_Float16*)(ws + OF_W1H);
  _Float16* wfh = (_Float16*)(ws + OF_WFH);
  int* idx2 = (int*)(ws + OF_I2);
  float* st = ws + OF_ST;
  float* ss0 = ws + OF_SS0;
  float* ss1 = ws + OF_SS1;
  float* ssd = ws + OF_SSD;
  float* sd0 = ws + OF_SD0;
  float* sd1 = ws + OF_SD1;

  float* out = (float*)d_out;
  float* out_idx = out + (size_t)BT * DIM;
  float* out_loss = out + (size_t)BT * DIM + (size_t)BT * QQ;

  hipMemsetAsync(out_loss, 0, sizeof(float), stream);

  // decoder weight conversions (f16)
  conv_f16<<<dim3(HID * DD / 4 / 256), 256, 0, stream>>>(dec_w0, w0h, HID * DD / 4);
  conv_f16<<<dim3(HID * HID / 4 / 256), 256, 0, stream>>>(dec_w1, w1h, HID * HID / 4);
  conv_f16<<<dim3(DIM * HID / 4 / 256), 256, 0, stream>>>(fin_w, wfh, DIM * HID / 4);

  // 1. transpose
  transpose_xt<<<dim3(TT / 32, DIM / 32, BB), dim3(32, 8), 0, stream>>>(x, xt);

  // 2. enc0: R1 = xt @ enc_w0^T + b0 (pre-BN), stats fused
  hipMemsetAsync(st, 0, 2 * HID * sizeof(float), stream);
  sgemm_f32<<<dim3(HID / 128, BT / 128), 256, 0, stream>>>(
      xt, DIM, enc_w0, DIM, enc_b0, R1, HID, DIM, nullptr, nullptr, 0, st, HID);
  bn_finalize<<<dim3(4), 256, 0, stream>>>(st, enc_g0, enc_be0, ss0, HID);

  // 3. enc1: R2 = relu(bn(R1)) @ enc_w1^T + b1, BN-apply fused into A-load
  hipMemsetAsync(st, 0, 2 * HID * sizeof(float), stream);
  sgemm_f32<<<dim3(HID / 128, BT / 128), 256, 0, stream>>>(
      R1, HID, enc_w1, HID, enc_b1, R2, HID, HID, ss0, ss0 + HID, 1, st, HID);
  bn_finalize<<<dim3(4), 256, 0, stream>>>(st, enc_g1, enc_be1, ss1, HID);

  // 4. per half: z (4 codebooks wide) into R1, then fused logits+argmax
  for (int h = 0; h < 2; h++) {
    sgemm_f32<<<dim3(HID / 128, BT / 128), 256, 0, stream>>>(
        R2, HID, enc_wo + (size_t)h * HID * HID, HID, enc_bo + h * HID,
        R1, HID, HID, ss1, ss1 + HID, 1, nullptr, 0);
    sgemm_logits<<<dim3(1, BT / 64, 4), 256, 0, stream>>>(
        R1, codebook, u, log_temps, h * 4, out_idx, idx2);
  }

  // 5. emb gather + BN -> f16
  emb_gather<<<dim3(BT), 256, 0, stream>>>(codebook, idx2, R1);
  hipMemsetAsync(st, 0, 2 * DD * sizeof(float), stream);
  colstats<<<dim3(1, 64), 256, 0, stream>>>(R1, DD, st);
  bn_finalize<<<dim3(1), 256, 0, stream>>>(st, dec_g, dec_be, ssd, DD);
  bn_apply_f16<<<dim3(2048), 256, 0, stream>>>(R1, ssd, DD - 1, DD,
                                               (long)BT * DD / 4, 0, embh);

  // 6. decoder FFN in f16 MFMA
  hipMemsetAsync(st, 0, 2 * HID * sizeof(float), stream);
  hgemm_nt<<<dim3(HID / 128, BT / 128), 256, 0, stream>>>(
      embh, w0h, dec_b0, R2, HID, DD, st, HID);
  bn_finalize<<<dim3(4), 256, 0, stream>>>(st, dec_g0, dec_be0, sd0, HID);
  bn_apply_f16<<<dim3(2048), 256, 0, stream>>>(R2, sd0, HID - 1, HID,
                                               (long)BT * HID / 4, 1, hbuf);

  hipMemsetAsync(st, 0, 2 * HID * sizeof(float), stream);
  hgemm_nt<<<dim3(HID / 128, BT / 128), 256, 0, stream>>>(
      hbuf, w1h, dec_b1, R1, HID, HID, st, HID);
  bn_finalize<<<dim3(4), 256, 0, stream>>>(st, dec_g1, dec_be1, sd1, HID);
  bn_apply_f16<<<dim3(2048), 256, 0, stream>>>(R1, sd1, HID - 1, HID,
                                               (long)BT * HID / 4, 1, hbuf);

  // 7. x_reco = h @ fin_w^T + fin_b
  hgemm_nt<<<dim3(DIM / 128, BT / 128), 256, 0, stream>>>(
      hbuf, wfh, fin_b, out, DIM, HID, nullptr, 0);

  // 8. commit loss
  loss_kernel<<<dim3(2048), 256, 0, stream>>>(out, xt, out_loss);
}

// Round 5
// 2152.183 us; speedup vs baseline: 1.1632x; 1.1632x over previous
//
#include <hip/hip_runtime.h>
#include <math.h>

#define BB   32
#define TT   512
#define DIM  512
#define HID  1024
#define QQ   8
#define CC   256
#define DD   256
#define BT   16384
#define EPSB 1e-5f

typedef _Float16 half4 __attribute__((ext_vector_type(4)));
typedef _Float16 half8 __attribute__((ext_vector_type(8)));
typedef float f32x4 __attribute__((ext_vector_type(4)));

#define GLOAD_LDS16(g, l)                                                      \
  __builtin_amdgcn_global_load_lds(                                            \
      (const __attribute__((address_space(1))) void*)(g),                      \
      (__attribute__((address_space(3))) void*)(l), 16, 0, 0)

// ---------------------------------------------------------------------------
// Transpose x (B, DIM, T) -> xt (B*T, DIM)
// ---------------------------------------------------------------------------
__global__ __launch_bounds__(256) void transpose_xt(const float* __restrict__ x,
                                                    float* __restrict__ xt) {
  __shared__ float tile[32][33];
  int tx = threadIdx.x, ty = threadIdx.y;
  int b = blockIdx.z;
  int t0 = blockIdx.x * 32, c0 = blockIdx.y * 32;
  const float* xb = x + (size_t)b * DIM * TT;
#pragma unroll
  for (int j = 0; j < 32; j += 8)
    tile[ty + j][tx] = xb[(size_t)(c0 + ty + j) * TT + (t0 + tx)];
  __syncthreads();
  float* xtb = xt + ((size_t)b * TT) * DIM;
#pragma unroll
  for (int j = 0; j < 32; j += 8)
    xtb[(size_t)(t0 + ty + j) * DIM + (c0 + tx)] = tile[tx][ty + j];
}

// ---------------------------------------------------------------------------
// fp32 NT GEMM: EXACT round-1 inner loop (405 us / 71% VALU proven; rounds
// 3/4 showed in-loop BN fusion costs ~100 us/dispatch -> de-fused).
// Epilogue-side column-stats fusion kept (harmless).
// ---------------------------------------------------------------------------
__global__ __launch_bounds__(256) void sgemm_f32(
    const float* __restrict__ A, int lda, const float* __restrict__ W, int ldw,
    const float* __restrict__ bias, float* __restrict__ C, int ldc, int K,
    float* __restrict__ stats, int N) {
  __shared__ float As[8][128];
  __shared__ float Ws[8][128];
  const int tid = threadIdx.x;
  const int m0 = blockIdx.y * 128, n0 = blockIdx.x * 128;
  const int lr = tid >> 1, lk = (tid & 1) << 2;
  const float* Ap = A + (size_t)(m0 + lr) * lda + lk;
  const float* Wp = W + (size_t)(n0 + lr) * ldw + lk;
  const int tm = (tid >> 4) << 3, tn = (tid & 15) << 3;

  float acc[8][8];
#pragma unroll
  for (int i = 0; i < 8; i++)
#pragma unroll
    for (int j = 0; j < 8; j++) acc[i][j] = 0.f;

  for (int kb = 0; kb < K; kb += 8) {
    float4 av = *(const float4*)(Ap + kb);
    float4 wv = *(const float4*)(Wp + kb);
    __syncthreads();
    As[lk + 0][lr] = av.x; As[lk + 1][lr] = av.y;
    As[lk + 2][lr] = av.z; As[lk + 3][lr] = av.w;
    Ws[lk + 0][lr] = wv.x; Ws[lk + 1][lr] = wv.y;
    Ws[lk + 2][lr] = wv.z; Ws[lk + 3][lr] = wv.w;
    __syncthreads();
#pragma unroll
    for (int k = 0; k < 8; ++k) {
      float a[8], b[8];
      *(float4*)(a) = *(const float4*)(&As[k][tm]);
      *(float4*)(a + 4) = *(const float4*)(&As[k][tm + 4]);
      *(float4*)(b) = *(const float4*)(&Ws[k][tn]);
      *(float4*)(b + 4) = *(const float4*)(&Ws[k][tn + 4]);
#pragma unroll
      for (int i = 0; i < 8; i++)
#pragma unroll
        for (int j = 0; j < 8; j++) acc[i][j] = fmaf(a[i], b[j], acc[i][j]);
    }
  }

  float bv[8], s1[8], s2[8];
#pragma unroll
  for (int j = 0; j < 8; j++) {
    bv[j] = bias ? bias[n0 + tn + j] : 0.f;
    s1[j] = 0.f; s2[j] = 0.f;
  }
#pragma unroll
  for (int i = 0; i < 8; i++) {
    float v[8];
#pragma unroll
    for (int j = 0; j < 8; j++) {
      v[j] = acc[i][j] + bv[j];
      s1[j] += v[j];
      s2[j] = fmaf(v[j], v[j], s2[j]);
    }
    float* Cp = C + (size_t)(m0 + tm + i) * ldc + (n0 + tn);
    float4 o;
    o.x = v[0]; o.y = v[1]; o.z = v[2]; o.w = v[3];
    *(float4*)Cp = o;
    o.x = v[4]; o.y = v[5]; o.z = v[6]; o.w = v[7];
    *(float4*)(Cp + 4) = o;
  }
  if (stats) {
#pragma unroll
    for (int j = 0; j < 8; j++) {
      s1[j] += __shfl_xor(s1[j], 16); s1[j] += __shfl_xor(s1[j], 32);
      s2[j] += __shfl_xor(s2[j], 16); s2[j] += __shfl_xor(s2[j], 32);
    }
    if ((tid & 48) == 0) {
#pragma unroll
      for (int j = 0; j < 8; j++) {
        atomicAdd(&stats[n0 + tn + j], s1[j]);
        atomicAdd(&stats[N + n0 + tn + j], s2[j]);
      }
    }
  }
}

// ---------------------------------------------------------------------------
// Wfold = blockdiag(cb_q) @ wo : NN GEMM, C[m,n] = sum_d cb[q, m&255, d] *
// wo[q*256+d, n], m = q*256+c. 128x128 tile, BK=8. Tiny (1.1 GF).
// ---------------------------------------------------------------------------
__global__ __launch_bounds__(256) void fold_w(const float* __restrict__ cb,
                                              const float* __restrict__ wo,
                                              float* __restrict__ Wf) {
  __shared__ float As[8][128];
  __shared__ float Ws[8][128];
  const int tid = threadIdx.x;
  const int n0 = blockIdx.x * 128;
  const int m0 = blockIdx.y * 128;
  const int q = m0 >> 8;
  const int lr = tid >> 1, lk = (tid & 1) << 2;
  const float* Ap = cb + (size_t)q * CC * DD + (size_t)((m0 & 255) + lr) * DD + lk;
  const int br = tid >> 5, bc = (tid & 31) << 2;
  const float* Bp = wo + (size_t)(q * CC + br) * HID + n0 + bc;
  const int tm = (tid >> 4) << 3, tn = (tid & 15) << 3;

  float acc[8][8];
#pragma unroll
  for (int i = 0; i < 8; i++)
#pragma unroll
    for (int j = 0; j < 8; j++) acc[i][j] = 0.f;

  for (int kb = 0; kb < DD; kb += 8) {
    float4 av = *(const float4*)(Ap + kb);
    float4 bb = *(const float4*)(Bp + (size_t)kb * HID);
    __syncthreads();
    As[lk + 0][lr] = av.x; As[lk + 1][lr] = av.y;
    As[lk + 2][lr] = av.z; As[lk + 3][lr] = av.w;
    *(float4*)&Ws[br][bc] = bb;
    __syncthreads();
#pragma unroll
    for (int k = 0; k < 8; ++k) {
      float a[8], b[8];
      *(float4*)(a) = *(const float4*)(&As[k][tm]);
      *(float4*)(a + 4) = *(const float4*)(&As[k][tm + 4]);
      *(float4*)(b) = *(const float4*)(&Ws[k][tn]);
      *(float4*)(b + 4) = *(const float4*)(&Ws[k][tn + 4]);
#pragma unroll
      for (int i = 0; i < 8; i++)
#pragma unroll
        for (int j = 0; j < 8; j++) acc[i][j] = fmaf(a[i], b[j], acc[i][j]);
    }
  }
#pragma unroll
  for (int i = 0; i < 8; i++) {
    float* Cp = Wf + (size_t)(m0 + tm + i) * HID + (n0 + tn);
    float4 o;
    o.x = acc[i][0]; o.y = acc[i][1]; o.z = acc[i][2]; o.w = acc[i][3];
    *(float4*)Cp = o;
    o.x = acc[i][4]; o.y = acc[i][5]; o.z = acc[i][6]; o.w = acc[i][7];
    *(float4*)(Cp + 4) = o;
  }
}

// bfold[q*256+c] = sum_d cb[q,c,d] * bo[q*256+d]
__global__ __launch_bounds__(256) void fold_b(const float* __restrict__ cb,
                                              const float* __restrict__ bo,
                                              float* __restrict__ bf) {
  int q = blockIdx.x, c = threadIdx.x;
  const float* row = cb + ((size_t)q * CC + c) * DD;
  const float* b = bo + q * DD;
  float s = 0.f;
  for (int d = 0; d < DD; d++) s = fmaf(row[d], b[d], s);
  bf[q * CC + c] = s;
}

// ---------------------------------------------------------------------------
// Fused wo-GEMM + dual argmax: logits[m, q*256+c] = H1[m,:] @ Wfold[q*256+c,:]
// + bfold. BM=128, BN=256 (full codebook per block), 512 threads, 8x8/thread
// (the proven inner-loop shape). Writes only indices — no logits to memory.
// ---------------------------------------------------------------------------
__global__ __launch_bounds__(512) void sgemm_wo_argmax(
    const float* __restrict__ A, const float* __restrict__ Wf,
    const float* __restrict__ bf, const float* __restrict__ u,
    const float* __restrict__ log_temps, float* __restrict__ out_idx,
    int* __restrict__ idx2) {
  __shared__ float As[8][128];
  __shared__ float Ws[8][256];
  const int tid = threadIdx.x;
  const int q = blockIdx.x;             // 0..7
  const int m0 = blockIdx.y * 128;
  const int n0 = q * CC;
  const int ar = tid >> 2, akk = (tid & 3) << 1;
  const float* Ap = A + (size_t)(m0 + ar) * HID + akk;
  const int wr = tid >> 1, wk = (tid & 1) << 2;
  const float* Wp = Wf + (size_t)(n0 + wr) * HID + wk;
  const int tm = (tid >> 5) << 3;       // 0..120
  const int tn = (tid & 31) << 3;       // 0..248

  float acc[8][8];
#pragma unroll
  for (int i = 0; i < 8; i++)
#pragma unroll
    for (int j = 0; j < 8; j++) acc[i][j] = 0.f;

  for (int kb = 0; kb < HID; kb += 8) {
    float2 av = *(const float2*)(Ap + kb);
    float4 wv = *(const float4*)(Wp + kb);
    __syncthreads();
    As[akk + 0][ar] = av.x; As[akk + 1][ar] = av.y;
    Ws[wk + 0][wr] = wv.x; Ws[wk + 1][wr] = wv.y;
    Ws[wk + 2][wr] = wv.z; Ws[wk + 3][wr] = wv.w;
    __syncthreads();
#pragma unroll
    for (int k = 0; k < 8; ++k) {
      float a[8], b[8];
      *(float4*)(a) = *(const float4*)(&As[k][tm]);
      *(float4*)(a + 4) = *(const float4*)(&As[k][tm + 4]);
      *(float4*)(b) = *(const float4*)(&Ws[k][tn]);
      *(float4*)(b + 4) = *(const float4*)(&Ws[k][tn + 4]);
#pragma unroll
      for (int i = 0; i < 8; i++)
#pragma unroll
        for (int j = 0; j < 8; j++) acc[i][j] = fmaf(a[i], b[j], acc[i][j]);
    }
  }

  const float scale = expf(-log_temps[q]);
  float bias[8];
#pragma unroll
  for (int j = 0; j < 8; j++) bias[j] = bf[n0 + tn + j];

#pragma unroll
  for (int i = 0; i < 8; i++) {
    const int row = m0 + tm + i;
    const float* urow = u + (size_t)row * (QQ * CC) + n0 + tn;
    float4 u0 = *(const float4*)(urow);
    float4 u1 = *(const float4*)(urow + 4);
    float uu[8] = {u0.x, u0.y, u0.z, u0.w, u1.x, u1.y, u1.z, u1.w};
    float bvv = -INFINITY; int bi = 0;
    float gv = -INFINITY; int gi = 0;
#pragma unroll
    for (int j = 0; j < 8; j++) {
      int c = tn + j;
      float v = acc[i][j] + bias[j];
      if (v > bvv) { bvv = v; bi = c; }
      float uc = fminf(fmaxf(uu[j], 1e-9f), 1.0f);
      float g = -logf(-logf(uc) + 1e-20f);
      float y = fmaf(v, scale, g);
      if (y > gv) { gv = y; gi = c; }
    }
#pragma unroll
    for (int off = 1; off < 32; off <<= 1) {
      float b2 = __shfl_xor(bvv, off); int bi2 = __shfl_xor(bi, off);
      if (b2 > bvv || (b2 == bvv && bi2 < bi)) { bvv = b2; bi = bi2; }
      float g2 = __shfl_xor(gv, off); int gi2 = __shfl_xor(gi, off);
      if (g2 > gv || (g2 == gv && gi2 < gi)) { gv = g2; gi = gi2; }
    }
    if ((tid & 31) == 0) {
      out_idx[(size_t)row * QQ + q] = (float)bi;
      idx2[(size_t)row * QQ + q] = gi;
    }
  }
}

// ---------------------------------------------------------------------------
// FP16 MFMA NT GEMM (m97 structure)
// ---------------------------------------------------------------------------
__global__ __launch_bounds__(256, 2) void hgemm_nt(
    const _Float16* __restrict__ A, const _Float16* __restrict__ W,
    const float* __restrict__ bias, float* __restrict__ C, int ldc, int K,
    float* __restrict__ stats, int N) {
  __shared__ _Float16 Al[4 * 128 * 8];
  __shared__ _Float16 Bl[4 * 128 * 8];
  const int tid = threadIdx.x;
  const int l = tid & 63;
  const int w = tid >> 6;
  const int m0 = blockIdx.y * 128, n0 = blockIdx.x * 128;
  const int wrow = (w >> 1) * 64, wcol = (w & 1) * 64;

  const int s0 = tid, s1 = tid + 256;
  const int r0 = s0 & 127, kp0 = s0 >> 7;
  const int r1 = s1 & 127, kp1 = s1 >> 7;
  const _Float16* Ag0 = A + (size_t)(m0 + r0) * K + kp0 * 8;
  const _Float16* Ag1 = A + (size_t)(m0 + r1) * K + kp1 * 8;
  const _Float16* Wg0 = W + (size_t)(n0 + r0) * K + kp0 * 8;
  const _Float16* Wg1 = W + (size_t)(n0 + r1) * K + kp1 * 8;
  _Float16* Al0 = &Al[s0 * 8]; _Float16* Al1 = &Al[s1 * 8];
  _Float16* Bl0 = &Bl[s0 * 8]; _Float16* Bl1 = &Bl[s1 * 8];

  f32x4 acc[4][4] = {};

  for (int kb = 0; kb < K; kb += 32) {
    __syncthreads();
    GLOAD_LDS16(Ag0 + kb, Al0);
    GLOAD_LDS16(Ag1 + kb, Al1);
    GLOAD_LDS16(Wg0 + kb, Bl0);
    GLOAD_LDS16(Wg1 + kb, Bl1);
    __syncthreads();
    half8 af[4], bf[4];
#pragma unroll
    for (int i = 0; i < 4; i++)
      af[i] = *(const half8*)&Al[(((l >> 4) << 7) + wrow + i * 16 + (l & 15)) * 8];
#pragma unroll
    for (int j = 0; j < 4; j++)
      bf[j] = *(const half8*)&Bl[(((l >> 4) << 7) + wcol + j * 16 + (l & 15)) * 8];
#pragma unroll
    for (int i = 0; i < 4; i++)
#pragma unroll
      for (int j = 0; j < 4; j++)
        acc[i][j] = __builtin_amdgcn_mfma_f32_16x16x32_f16(af[i], bf[j],
                                                           acc[i][j], 0, 0, 0);
  }

#pragma unroll
  for (int j = 0; j < 4; j++) {
    const int col = n0 + wcol + j * 16 + (l & 15);
    const float bb = bias[col];
    float s1v = 0.f, s2v = 0.f;
#pragma unroll
    for (int i = 0; i < 4; i++) {
#pragma unroll
      for (int r = 0; r < 4; r++) {
        float v = acc[i][j][r] + bb;
        const int row = m0 + wrow + i * 16 + ((l >> 4) << 2) + r;
        C[(size_t)row * ldc + col] = v;
        s1v += v;
        s2v = fmaf(v, v, s2v);
      }
    }
    if (stats) {
      s1v += __shfl_xor(s1v, 16); s1v += __shfl_xor(s1v, 32);
      s2v += __shfl_xor(s2v, 16); s2v += __shfl_xor(s2v, 32);
      if (l < 16) {
        atomicAdd(&stats[col], s1v);
        atomicAdd(&stats[N + col], s2v);
      }
    }
  }
}

// ---------------------------------------------------------------------------
// BatchNorm helpers
// ---------------------------------------------------------------------------
__global__ __launch_bounds__(256) void colstats(const float* __restrict__ h, int N,
                                                float* __restrict__ sums) {
  int col = blockIdx.x * 256 + threadIdx.x;
  size_t base = (size_t)blockIdx.y * 256 * N + col;
  float s = 0.f, s2 = 0.f;
  for (int r = 0; r < 256; r++) {
    float v = h[base + (size_t)r * N];
    s += v;
    s2 = fmaf(v, v, s2);
  }
  atomicAdd(&sums[col], s);
  atomicAdd(&sums[N + col], s2);
}

__global__ __launch_bounds__(256) void bn_finalize(const float* __restrict__ sums,
                                                   const float* __restrict__ gamma,
                                                   const float* __restrict__ beta,
                                                   float* __restrict__ ss, int N) {
  int n = blockIdx.x * 256 + threadIdx.x;
  if (n >= N) return;
  const float invM = 1.0f / (float)BT;
  float mean = sums[n] * invM;
  float var = sums[N + n] * invM - mean * mean;
  float sc = gamma[n] / sqrtf(var + EPSB);
  ss[n] = sc;
  ss[N + n] = beta[n] - mean * sc;
}

// in-place fp32 BN apply (+relu) — de-fused from the GEMM (rounds 3/4 lesson)
__global__ __launch_bounds__(256) void bn_apply(float* __restrict__ h,
                                                const float* __restrict__ ss,
                                                int nmask, int N, long n4,
                                                int relu) {
  long stride = (long)gridDim.x * 256;
  for (long i = (long)blockIdx.x * 256 + threadIdx.x; i < n4; i += stride) {
    int col = (int)((i << 2) & nmask);
    float4 v = ((float4*)h)[i];
    float4 sc = *(const float4*)(ss + col);
    float4 sh = *(const float4*)(ss + N + col);
    v.x = fmaf(v.x, sc.x, sh.x); v.y = fmaf(v.y, sc.y, sh.y);
    v.z = fmaf(v.z, sc.z, sh.z); v.w = fmaf(v.w, sc.w, sh.w);
    if (relu) {
      v.x = fmaxf(v.x, 0.f); v.y = fmaxf(v.y, 0.f);
      v.z = fmaxf(v.z, 0.f); v.w = fmaxf(v.w, 0.f);
    }
    ((float4*)h)[i] = v;
  }
}

// fp32 h -> f16 out with BN scale/shift (+optional relu)
__global__ __launch_bounds__(256) void bn_apply_f16(const float* __restrict__ h,
                                                    const float* __restrict__ ss,
                                                    int nmask, int N, long n4,
                                                    int relu,
                                                    _Float16* __restrict__ o) {
  long stride = (long)gridDim.x * 256;
  for (long i = (long)blockIdx.x * 256 + threadIdx.x; i < n4; i += stride) {
    int col = (int)((i << 2) & nmask);
    float4 v = ((const float4*)h)[i];
    float4 sc = *(const float4*)(ss + col);
    float4 sh = *(const float4*)(ss + N + col);
    v.x = fmaf(v.x, sc.x, sh.x); v.y = fmaf(v.y, sc.y, sh.y);
    v.z = fmaf(v.z, sc.z, sh.z); v.w = fmaf(v.w, sc.w, sh.w);
    if (relu) {
      v.x = fmaxf(v.x, 0.f); v.y = fmaxf(v.y, 0.f);
      v.z = fmaxf(v.z, 0.f); v.w = fmaxf(v.w, 0.f);
    }
    half4 hv;
    hv.x = (_Float16)v.x; hv.y = (_Float16)v.y;
    hv.z = (_Float16)v.z; hv.w = (_Float16)v.w;
    ((half4*)o)[i] = hv;
  }
}

__global__ __launch_bounds__(256) void conv_f16(const float* __restrict__ in,
                                                _Float16* __restrict__ o, int n4) {
  int i = blockIdx.x * 256 + threadIdx.x;
  if (i >= n4) return;
  float4 v = ((const float4*)in)[i];
  half4 hv;
  hv.x = (_Float16)v.x; hv.y = (_Float16)v.y;
  hv.z = (_Float16)v.z; hv.w = (_Float16)v.w;
  ((half4*)o)[i] = hv;
}

// ---------------------------------------------------------------------------
// emb[bt, d] = sum_q codebook[q, idx2[bt,q], d]
// ---------------------------------------------------------------------------
__global__ __launch_bounds__(256) void emb_gather(const float* __restrict__ cb,
                                                  const int* __restrict__ idx2,
                                                  float* __restrict__ emb) {
  __shared__ int k[QQ];
  int bt = blockIdx.x;
  int d = threadIdx.x;
  if (d < QQ) k[d] = idx2[bt * QQ + d];
  __syncthreads();
  float s = 0.f;
#pragma unroll
  for (int q = 0; q < QQ; q++) s += cb[((size_t)(q * CC + k[q])) * DD + d];
  emb[(size_t)bt * DD + d] = s;
}

// ---------------------------------------------------------------------------
// commit loss
// ---------------------------------------------------------------------------
__global__ __launch_bounds__(256) void loss_kernel(const float* __restrict__ xr,
                                                   const float* __restrict__ xt,
                                                   float* __restrict__ out) {
  const long n4 = (long)BT * DIM / 4;
  float s = 0.f;
  long stride = (long)gridDim.x * 256;
  for (long i = (long)blockIdx.x * 256 + threadIdx.x; i < n4; i += stride) {
    float4 a = ((const float4*)xr)[i];
    float4 b = ((const float4*)xt)[i];
    float dx = a.x - b.x, dy = a.y - b.y, dz = a.z - b.z, dw = a.w - b.w;
    s = fmaf(dx, dx, s); s = fmaf(dy, dy, s);
    s = fmaf(dz, dz, s); s = fmaf(dw, dw, s);
  }
#pragma unroll
  for (int off = 32; off > 0; off >>= 1) s += __shfl_down(s, off);
  __shared__ float red[4];
  if ((threadIdx.x & 63) == 0) red[threadIdx.x >> 6] = s;
  __syncthreads();
  if (threadIdx.x == 0)
    atomicAdd(out, (red[0] + red[1] + red[2] + red[3]) * (1.0f / (float)(BT * DIM)));
}

// ---------------------------------------------------------------------------
// Workspace layout (float offsets), total ~55.6M floats = 222 MB
// (round-1 layout used 236 MB successfully -> within budget)
// ---------------------------------------------------------------------------
static const size_t OF_XT = 0;
static const size_t OF_R1 = OF_XT + (size_t)BT * DIM;
static const size_t OF_R2 = OF_R1 + (size_t)BT * HID;
static const size_t OF_WF = OF_R2 + (size_t)BT * HID;          // 2048*1024
static const size_t OF_BF = OF_WF + (size_t)2048 * HID;        // 2048
static const size_t OF_EMBH = OF_BF + 2048;
static const size_t OF_HB = OF_EMBH + (size_t)BT * DD / 2;
static const size_t OF_W0H = OF_HB + (size_t)BT * HID / 2;
static const size_t OF_W1H = OF_W0H + (size_t)HID * DD / 2;
static const size_t OF_WFH = OF_W1H + (size_t)HID * HID / 2;
static const size_t OF_I2 = OF_WFH + (size_t)DIM * HID / 2;
static const size_t OF_ST = OF_I2 + (size_t)BT * QQ;
static const size_t OF_SS0 = OF_ST + 4096;
static const size_t OF_SS1 = OF_SS0 + 2048;
static const size_t OF_SSD = OF_SS1 + 2048;
static const size_t OF_SD0 = OF_SSD + 1024;
static const size_t OF_SD1 = OF_SD0 + 2048;

extern "C" void kernel_launch(void* const* d_in, const int* in_sizes, int n_in,
                              void* d_out, int out_size, void* d_ws, size_t ws_size,
                              hipStream_t stream) {
  const float* x        = (const float*)d_in[0];
  const float* u        = (const float*)d_in[1];
  const float* codebook = (const float*)d_in[2];
  const float* log_temps= (const float*)d_in[3];
  const float* enc_w0   = (const float*)d_in[4];
  const float* enc_b0   = (const float*)d_in[5];
  const float* enc_g0   = (const float*)d_in[6];
  const float* enc_be0  = (const float*)d_in[7];
  const float* enc_w1   = (const float*)d_in[8];
  const float* enc_b1   = (const float*)d_in[9];
  const float* enc_g1   = (const float*)d_in[10];
  const float* enc_be1  = (const float*)d_in[11];
  const float* enc_wo   = (const float*)d_in[12];
  const float* enc_bo   = (const float*)d_in[13];
  const float* dec_g    = (const float*)d_in[14];
  const float* dec_be   = (const float*)d_in[15];
  const float* dec_w0   = (const float*)d_in[16];
  const float* dec_b0   = (const float*)d_in[17];
  const float* dec_g0   = (const float*)d_in[18];
  const float* dec_be0  = (const float*)d_in[19];
  const float* dec_w1   = (const float*)d_in[20];
  const float* dec_b1   = (const float*)d_in[21];
  const float* dec_g1   = (const float*)d_in[22];
  const float* dec_be1  = (const float*)d_in[23];
  const float* fin_w    = (const float*)d_in[24];
  const float* fin_b    = (const float*)d_in[25];

  float* ws = (float*)d_ws;
  float* xt = ws + OF_XT;
  float* R1 = ws + OF_R1;
  float* R2 = ws + OF_R2;
  float* Wf = ws + OF_WF;
  float* bfold = ws + OF_BF;
  _Float16* embh = (_Float16*)(ws + OF_EMBH);
  _Float16* hbuf = (_Float16*)(ws + OF_HB);
  _Float16* w0h = (_Float16*)(ws + OF_W0H);
  _Float16* w1h = (_Float16*)(ws + OF_W1H);
  _Float16* wfh = (_Float16*)(ws + OF_WFH);
  int* idx2 = (int*)(ws + OF_I2);
  float* st = ws + OF_ST;
  float* ss0 = ws + OF_SS0;
  float* ss1 = ws + OF_SS1;
  float* ssd = ws + OF_SSD;
  float* sd0 = ws + OF_SD0;
  float* sd1 = ws + OF_SD1;

  float* out = (float*)d_out;
  float* out_idx = out + (size_t)BT * DIM;
  float* out_loss = out + (size_t)BT * DIM + (size_t)BT * QQ;

  hipMemsetAsync(out_loss, 0, sizeof(float), stream);

  // decoder weight conversions (f16) + codebook folding
  conv_f16<<<dim3(HID * DD / 4 / 256), 256, 0, stream>>>(dec_w0, w0h, HID * DD / 4);
  conv_f16<<<dim3(HID * HID / 4 / 256), 256, 0, stream>>>(dec_w1, w1h, HID * HID / 4);
  conv_f16<<<dim3(DIM * HID / 4 / 256), 256, 0, stream>>>(fin_w, wfh, DIM * HID / 4);
  fold_w<<<dim3(HID / 128, 2048 / 128), 256, 0, stream>>>(codebook, enc_wo, Wf);
  fold_b<<<dim3(QQ), 256, 0, stream>>>(codebook, enc_bo, bfold);

  // 1. transpose
  transpose_xt<<<dim3(TT / 32, DIM / 32, BB), dim3(32, 8), 0, stream>>>(x, xt);

  // 2. enc0: R1 = xt @ enc_w0^T + b0 (pre-BN), stats fused; then BN in place
  hipMemsetAsync(st, 0, 2 * HID * sizeof(float), stream);
  sgemm_f32<<<dim3(HID / 128, BT / 128), 256, 0, stream>>>(
      xt, DIM, enc_w0, DIM, enc_b0, R1, HID, DIM, st, HID);
  bn_finalize<<<dim3(4), 256, 0, stream>>>(st, enc_g0, enc_be0, ss0, HID);
  bn_apply<<<dim3(2048), 256, 0, stream>>>(R1, ss0, HID - 1, HID,
                                           (long)BT * HID / 4, 1);

  // 3. enc1: R2 = R1 @ enc_w1^T + b1, stats fused; BN in place
  hipMemsetAsync(st, 0, 2 * HID * sizeof(float), stream);
  sgemm_f32<<<dim3(HID / 128, BT / 128), 256, 0, stream>>>(
      R1, HID, enc_w1, HID, enc_b1, R2, HID, HID, st, HID);
  bn_finalize<<<dim3(4), 256, 0, stream>>>(st, enc_g1, enc_be1, ss1, HID);
  bn_apply<<<dim3(2048), 256, 0, stream>>>(R2, ss1, HID - 1, HID,
                                           (long)BT * HID / 4, 1);

  // 4. folded wo-GEMM + argmax epilogue (no logits materialization)
  sgemm_wo_argmax<<<dim3(QQ, BT / 128), 512, 0, stream>>>(
      R2, Wf, bfold, u, log_temps, out_idx, idx2);

  // 5. emb gather + BN -> f16
  emb_gather<<<dim3(BT), 256, 0, stream>>>(codebook, idx2, R1);
  hipMemsetAsync(st, 0, 2 * DD * sizeof(float), stream);
  colstats<<<dim3(1, 64), 256, 0, stream>>>(R1, DD, st);
  bn_finalize<<<dim3(1), 256, 0, stream>>>(st, dec_g, dec_be, ssd, DD);
  bn_apply_f16<<<dim3(2048), 256, 0, stream>>>(R1, ssd, DD - 1, DD,
                                               (long)BT * DD / 4, 0, embh);

  // 6. decoder FFN in f16 MFMA
  hipMemsetAsync(st, 0, 2 * HID * sizeof(float), stream);
  hgemm_nt<<<dim3(HID / 128, BT / 128), 256, 0, stream>>>(
      embh, w0h, dec_b0, R2, HID, DD, st, HID);
  bn_finalize<<<dim3(4), 256, 0, stream>>>(st, dec_g0, dec_be0, sd0, HID);
  bn_apply_f16<<<dim3(2048), 256, 0, stream>>>(R2, sd0, HID - 1, HID,
                                               (long)BT * HID / 4, 1, hbuf);

  hipMemsetAsync(st, 0, 2 * HID * sizeof(float), stream);
  hgemm_nt<<<dim3(HID / 128, BT / 128), 256, 0, stream>>>(
      hbuf, w1h, dec_b1, R1, HID, HID, st, HID);
  bn_finalize<<<dim3(4), 256, 0, stream>>>(st, dec_g1, dec_be1, sd1, HID);
  bn_apply_f16<<<dim3(2048), 256, 0, stream>>>(R1, sd1, HID - 1, HID,
                                               (long)BT * HID / 4, 1, hbuf);

  // 7. x_reco = h @ fin_w^T + fin_b
  hgemm_nt<<<dim3(DIM / 128, BT / 128), 256, 0, stream>>>(
      hbuf, wfh, fin_b, out, DIM, HID, nullptr, 0);

  // 8. commit loss
  loss_kernel<<<dim3(2048), 256, 0, stream>>>(out, xt, out_loss);
}